// Round 4
// baseline (245.225 us; speedup 1.0000x reference)
//
#include <hip/hip_runtime.h>

#define T_LEN 1024

typedef _Float16 f16x8 __attribute__((ext_vector_type(8)));
typedef __fp16   fp16x2 __attribute__((ext_vector_type(2)));
typedef float    f32x4 __attribute__((ext_vector_type(4)));
typedef float    f32x2 __attribute__((ext_vector_type(2)));

// One wave (64 threads) per block; block owns 16 batch rows for all T steps.
// REGIME (R0-R3): all 1024 waves co-resident (1/SIMD); wall time = T x
// per-step pipe time. R3 established we are ~74% VALU/TRANS-occupancy bound:
// busy cycles/step ~265 of 358, dominated by 16 trans ops x ~14cy. Levers are
// (a) fewer trans ops, (b) fewer VALU ops, (c) less stall. R3 did (b)+(c).
// THIS ROUND (a): rcp PAIRING -- two sigmoids share one v_rcp_f32:
//   p = rcp(d0*d1); r0 = d1*p; r1 = d0*p
// trades 1 trans (~14cy) for ~2 packed/scalar muls (~4cy) per pair:
// trans count 16 -> 12 per step, net ~-40cy occupancy. Chains per pair stay
// independent so latency exposure is unchanged. d0*d1 <= ~2^40, no overflow.
// Accuracy ~3ulp f32 << f16 recirculation quantum.
//
// Recurrence in "r-space": h = 1 - 2r, r = 1/(exp2(t)+1), t = K*v, K = 2*log2(e).
//   t[c] = K*(x*Wih[c] + b[c] + rowsum(W_hh[c,:])) + sum_k (-2K*W_hh[c,k]) * r[k]
// A-frag = -2K*W_hh (f16); r recirculates directly as the B-fragment.
//   A-frag: A[m=lane&15][k=quad*8+j] = -2K*Whh[sigma(m)][k]
//   B-frag: B[k=quad*8+j][n=lane&15] = r[row n][k]
//   C-frag: col n=lane&15 (batch row), row m=quad*4+reg; sigma0(m)=8*(m>>2)+(m&3),
//   sigma1=sigma0+4 ==> lane's C outputs are exactly its own B slots next step.
__device__ __forceinline__ fp16x2 sig_pair(float t0, float t1) {
    // (sigmoid of -t in r-space) for two values with ONE rcp.
    f32x2 d = { __builtin_amdgcn_exp2f(t0), __builtin_amdgcn_exp2f(t1) };
    d += 1.0f;                                    // v_pk_add_f32
    float p = __builtin_amdgcn_rcpf(d.x * d.y);   // 1 mul + 1 trans
    f32x2 sw = { d.y, d.x };                      // op_sel swap (free in VOP3P)
    f32x2 pp = { p, p };
    f32x2 rr = sw * pp;                           // v_pk_mul_f32: {r0, r1}
    return __builtin_amdgcn_cvt_pkrtz(rr.x, rr.y);
}

__global__ __launch_bounds__(64) void rnn_fused(
    const float* __restrict__ x,      // [B, T]
    const float* __restrict__ W_ih,   // [32,1]
    const float* __restrict__ W_hh,   // [32,32]
    const float* __restrict__ b_ih,   // [32]
    const float* __restrict__ b_hh,   // [32]
    const float* __restrict__ fc_w,   // [1,32]
    const float* __restrict__ fc_b,   // [1]
    float* __restrict__ out)          // [B]
{
    const int lane = threadIdx.x;
    const int n = lane & 15;   // batch row within tile (B-frag col / C col)
    const int q = lane >> 4;   // quad index

    const float K = 2.88539008177792681472f;   // 2*log2(e)

    // A fragments: -2K * W_hh rows (permuted by sigma), f16.
    const int c0row = 8 * (n >> 2) + (n & 3);
    const int c1row = c0row + 4;
    f16x8 a0, a1;
#pragma unroll
    for (int j = 0; j < 8; ++j) {
        a0[j] = (_Float16)(-2.0f * K * W_hh[c0row * 32 + q * 8 + j]);
        a1[j] = (_Float16)(-2.0f * K * W_hh[c1row * 32 + q * 8 + j]);
    }

    // This lane produces h-columns c = 8q + i (i = 0..7), as f32x4 vectors so
    // the C-init compiles to v_pk_fma_f32 (packed, full rate, IEEE-identical).
    // bias' = K*(b_ih + b_hh + rowsum(W_hh[c,:]))  (r-space fold)
    f32x4 wv0, wv1, bv0, bv1;
#pragma unroll
    for (int i = 0; i < 8; ++i) {
        int c = 8 * q + i;
        float rs = 0.0f;
        for (int k = 0; k < 32; ++k) rs += W_hh[c * 32 + k];
        float wihc  = K * W_ih[c];
        float biasc = K * (b_ih[c] + b_hh[c] + rs);
        if (i < 4) { wv0[i] = wihc; bv0[i] = biasc; }
        else       { wv1[i - 4] = wihc; bv1[i - 4] = biasc; }
    }

    const float* xrow = x + (size_t)(blockIdx.x * 16 + n) * T_LEN;
    float4 xa = *(const float4*)xrow;   // t = 0..3 (4 lanes/row redundant -> broadcast)

    // B fragment holds r; h=0 <=> r=0.5
    f16x8 hb;
#pragma unroll
    for (int i = 0; i < 8; ++i) hb[i] = (_Float16)0.5f;

    for (int t4 = 0; t4 < T_LEN / 4; ++t4) {
        const int nt4 = (t4 < T_LEN / 4 - 1) ? t4 + 1 : t4;   // prefetch next x chunk
        float4 xn = *(const float4*)(xrow + (size_t)nt4 * 4);
#pragma unroll
        for (int p = 0; p < 4; ++p) {
            const float xt = (p == 0) ? xa.x : (p == 1) ? xa.y : (p == 2) ? xa.z : xa.w;
            const f32x4 xt4 = {xt, xt, xt, xt};
            // C-init = K*(x*Wih + b + rowsum): 2x v_pk_fma_f32 per acc
            f32x4 acc0 = __builtin_elementwise_fma(xt4, wv0, bv0);
            f32x4 acc1 = __builtin_elementwise_fma(xt4, wv1, bv1);
            acc0 = __builtin_amdgcn_mfma_f32_16x16x32_f16(a0, hb, acc0, 0, 0, 0);
            acc1 = __builtin_amdgcn_mfma_f32_16x16x32_f16(a1, hb, acc1, 0, 0, 0);

            // Paired epilogue: per pair {2 exp, pk_add, mul, rcp, pk_mul, cvt}
            // 12 trans/step instead of 16; 4 independent pair-chains interleave.
            struct H4 { fp16x2 p[4]; } hh;
            hh.p[0] = sig_pair(acc0[0], acc0[1]);
            hh.p[1] = sig_pair(acc0[2], acc0[3]);
            hh.p[2] = sig_pair(acc1[0], acc1[1]);
            hh.p[3] = sig_pair(acc1[2], acc1[3]);
            hb = __builtin_bit_cast(f16x8, hh);
        }
        xa = xn;
    }

    // Head: h = 1 - 2r; out[row] = sum_c h[c] * fc_w[c] + fc_b
    float part = 0.0f;
#pragma unroll
    for (int i = 0; i < 8; ++i) {
        float h = fmaf(-2.0f, (float)hb[i], 1.0f);
        part = fmaf(h, fc_w[8 * q + i], part);
    }
    part += __shfl_xor(part, 16);
    part += __shfl_xor(part, 32);
    if (q == 0) out[blockIdx.x * 16 + n] = part + fc_b[0];
}

extern "C" void kernel_launch(void* const* d_in, const int* in_sizes, int n_in,
                              void* d_out, int out_size, void* d_ws, size_t ws_size,
                              hipStream_t stream) {
    const float* x    = (const float*)d_in[0];
    const float* W_ih = (const float*)d_in[1];
    const float* W_hh = (const float*)d_in[2];
    const float* b_ih = (const float*)d_in[3];
    const float* b_hh = (const float*)d_in[4];
    const float* fc_w = (const float*)d_in[5];
    const float* fc_b = (const float*)d_in[6];
    float* out = (float*)d_out;

    const int B = in_sizes[0] / T_LEN;   // 16384
    rnn_fused<<<B / 16, 64, 0, stream>>>(x, W_ih, W_hh, b_ih, b_hh, fc_w, fc_b, out);
}